// Round 5
// baseline (44.276 us; speedup 1.0000x reference)
//
#include <hip/hip_runtime.h>

#define CC 8
#define HW 4096
#define L2E 1.4426950408889634f

typedef __attribute__((ext_vector_type(4))) float f32x4;

// Single fused kernel: 256 blocks (4 batches x 64 pixel-tiles) x 1024 threads.
// Each block is self-sufficient (no inter-block deps, no workspace):
//   phase 1a: all threads compute (pk*log2e, pv) for 4 m's each -> kv[] LDS
//   phase 1b: all threads compute pq for their lane's pixel (+ keep xn[8] regs)
//   phase 1c: waves 0-3 (one per SIMD) redundantly compute the 8x8 Gram + rowsums
//   phase 2 : 16 waves x 256-m segments; k/v fed by broadcast ds_read_b128
//   phase 3 : wave 0 combines PAM partials + CAM 8x8 softmax
//   phase 4 : waves 0-7 write the fused epilogue
__global__ __launch_bounds__(1024, 4) void fused_attn(
    const float* __restrict__ x,
    const float* __restrict__ cwq, const float* __restrict__ cbq,
    const float* __restrict__ cwk, const float* __restrict__ cbk,
    const float* __restrict__ cwv, const float* __restrict__ cbv,
    const float* __restrict__ pwq, const float* __restrict__ pbq,
    const float* __restrict__ pwk, const float* __restrict__ pbk,
    const float* __restrict__ pwv, const float* __restrict__ pbv,
    float* __restrict__ out)
{
  const int b = blockIdx.x >> 6, tile = blockIdx.x & 63;
  const int n0 = tile * 64;
  const int t = threadIdx.x, ln = t & 63;
  const int wid = __builtin_amdgcn_readfirstlane(t >> 6);   // wave 0..15

  __shared__ __align__(16) float kv[HW * 2];                // 32 KB (k2,v interleaved)
  __shared__ float redd[16][64], redn[16][64];              // 8 KB
  __shared__ float gpart[4][44];
  __shared__ float sums[44], Gl[64], Ll[64], Al[64], Mp[64], cvs[8], outp[64];

  const float* xb = x + b * CC * HW;

  // ---- phase 1a: kv for my 4 m's (m = 4t..4t+3), coalesced float4 loads ----
  {
    const int m4 = t * 4;
    f32x4 xc[CC];
    #pragma unroll
    for (int c = 0; c < CC; ++c)
      xc[c] = *(const f32x4*)(xb + c * HW + m4);
    f32x4 kk, vv;
    #pragma unroll
    for (int j = 0; j < 4; ++j) {
      float k = pbk[0], v = pbv[0];
      #pragma unroll
      for (int c = 0; c < CC; ++c) {
        k = fmaf(pwk[c], xc[c][j], k);
        v = fmaf(pwv[c], xc[c][j], v);
      }
      kk[j] = k * L2E; vv[j] = v;
    }
    f32x4* kv4 = (f32x4*)kv;
    f32x4 w0, w1;
    w0[0] = kk[0]; w0[1] = vv[0]; w0[2] = kk[1]; w0[3] = vv[1];
    w1[0] = kk[2]; w1[1] = vv[2]; w1[2] = kk[3]; w1[3] = vv[3];
    kv4[2 * t] = w0; kv4[2 * t + 1] = w1;
  }

  // ---- phase 1b: pq for pixel n0+ln (all waves need it); keep xn for epilogue ----
  float xn[CC];
  #pragma unroll
  for (int c = 0; c < CC; ++c) xn[c] = xb[c * HW + n0 + ln];
  float a = pbq[0];
  #pragma unroll
  for (int c = 0; c < CC; ++c) a = fmaf(pwq[c], xn[c], a);

  // ---- phase 1c: Gram + rowsums, waves 0-3 only (16 px per thread) ----
  if (wid < 4) {
    float acc[44];
    #pragma unroll
    for (int i = 0; i < 44; ++i) acc[i] = 0.f;
    const int p0 = t * 16;
    #pragma unroll
    for (int blk = 0; blk < 4; ++blk) {
      f32x4 xq[CC];
      #pragma unroll
      for (int c = 0; c < CC; ++c)
        xq[c] = *(const f32x4*)(xb + c * HW + p0 + blk * 4);
      #pragma unroll
      for (int j = 0; j < 4; ++j) {
        int k = 0;
        #pragma unroll
        for (int c = 0; c < CC; ++c) {
          #pragma unroll
          for (int d = c; d < CC; ++d) { acc[k] = fmaf(xq[c][j], xq[d][j], acc[k]); ++k; }
        }
        #pragma unroll
        for (int c = 0; c < CC; ++c) acc[36 + c] += xq[c][j];
      }
    }
    #pragma unroll
    for (int i = 0; i < 44; ++i) {
      float v = acc[i];
      #pragma unroll
      for (int off = 32; off > 0; off >>= 1) v += __shfl_xor(v, off, 64);
      acc[i] = v;
    }
    if (ln == 0) {
      #pragma unroll
      for (int i = 0; i < 44; ++i) gpart[wid][i] = acc[i];
    }
  }
  __syncthreads();

  // ---- phase 2: PAM rank-1 softmax; wave wid handles m in [wid*256, wid*256+256) ----
  {
    const f32x4* kvw = ((const f32x4*)kv) + (wid << 7);     // 128 f32x4 = 256 m
    float dA = 0, dB = 0, dC = 0, dD = 0;
    float nA = 0, nB = 0, nC = 0, nD = 0;
    #pragma unroll 2
    for (int i = 0; i < 128; i += 4) {
      const f32x4 p0 = kvw[i], p1 = kvw[i + 1], p2 = kvw[i + 2], p3 = kvw[i + 3];
      float e;
      e = __builtin_amdgcn_exp2f(a * p0[0]); dA += e; nA = fmaf(e, p0[1], nA);
      e = __builtin_amdgcn_exp2f(a * p0[2]); dA += e; nA = fmaf(e, p0[3], nA);
      e = __builtin_amdgcn_exp2f(a * p1[0]); dB += e; nB = fmaf(e, p1[1], nB);
      e = __builtin_amdgcn_exp2f(a * p1[2]); dB += e; nB = fmaf(e, p1[3], nB);
      e = __builtin_amdgcn_exp2f(a * p2[0]); dC += e; nC = fmaf(e, p2[1], nC);
      e = __builtin_amdgcn_exp2f(a * p2[2]); dC += e; nC = fmaf(e, p2[3], nC);
      e = __builtin_amdgcn_exp2f(a * p3[0]); dD += e; nD = fmaf(e, p3[1], nD);
      e = __builtin_amdgcn_exp2f(a * p3[2]); dD += e; nD = fmaf(e, p3[3], nD);
    }
    redd[wid][ln] = (dA + dB) + (dC + dD);
    redn[wid][ln] = (nA + nB) + (nC + nD);
  }
  __syncthreads();

  // ---- phase 3: wave 0: PAM combine + CAM 8x8 softmax ----
  if (t < 64) {
    float D = 0.f, N = 0.f;
    #pragma unroll
    for (int s = 0; s < 16; ++s) { D += redd[s][t]; N += redn[s][t]; }
    outp[t] = N / D;
  }
  if (t < 44)
    sums[t] = gpart[0][t] + gpart[1][t] + gpart[2][t] + gpart[3][t];
  __syncthreads();

  const int c = ln >> 3, d = ln & 7;
  if (t < 64) {
    const int lo = min(c, d), hi = max(c, d);
    Gl[t] = sums[lo * 8 + hi - lo * (lo + 1) / 2];
  }
  __syncthreads();

  float Lv = 0.f;
  if (t < 64) {
    float qs = 0.f, ks = 0.f;
    #pragma unroll
    for (int e = 0; e < 8; ++e) {
      qs = fmaf(cwq[c * 8 + e], sums[36 + e], qs);
      ks = fmaf(cwk[d * 8 + e], sums[36 + e], ks);
    }
    float A = 0.f;
    #pragma unroll
    for (int e = 0; e < 8; ++e) {
      float inner = 0.f;
      #pragma unroll
      for (int f = 0; f < 8; ++f) inner = fmaf(Gl[e * 8 + f], cwk[d * 8 + f], inner);
      A = fmaf(cwq[c * 8 + e], inner, A);
    }
    Lv = A + qs * cbk[d] + cbq[c] * ks + 4096.f * cbq[c] * cbk[d];
    Ll[t] = Lv;
  }
  __syncthreads();

  if (t < 64) {
    float mx = -INFINITY;
    #pragma unroll
    for (int f = 0; f < 8; ++f) mx = fmaxf(mx, Ll[c * 8 + f]);
    float ssum = 0.f;
    #pragma unroll
    for (int f = 0; f < 8; ++f) ssum += __expf(Ll[c * 8 + f] - mx);
    Al[t] = __expf(Lv - mx) / ssum;
  }
  __syncthreads();

  if (t < 64) {
    float M = 0.f;
    #pragma unroll
    for (int f = 0; f < 8; ++f) M = fmaf(Al[c * 8 + f], cwv[f * 8 + d], M);
    if (d == c) M += 2.f;            // +2I: residual x appears in both CAM and PAM
    Mp[t] = M;
    if (d == 0) {
      float cvv = 0.f;
      #pragma unroll
      for (int f = 0; f < 8; ++f) cvv = fmaf(Al[c * 8 + f], cbv[f], cvv);
      cvs[c] = cvv;
    }
  }
  __syncthreads();

  // ---- phase 4: epilogue, waves 0-7: channel w for all 64 pixels (xn reused) ----
  if (t < 512) {
    const int w = wid;
    float o = cvs[w] + outp[ln];
    #pragma unroll
    for (int dd = 0; dd < 8; ++dd) o = fmaf(Mp[w * 8 + dd], xn[dd], o);
    out[(b * 8 + w) * HW + n0 + ln] = o;
  }
}

extern "C" void kernel_launch(void* const* d_in, const int* in_sizes, int n_in,
                              void* d_out, int out_size, void* d_ws, size_t ws_size,
                              hipStream_t stream) {
  const float* x   = (const float*)d_in[0];
  const float* cwq = (const float*)d_in[1];
  const float* cbq = (const float*)d_in[2];
  const float* cwk = (const float*)d_in[3];
  const float* cbk = (const float*)d_in[4];
  const float* cwv = (const float*)d_in[5];
  const float* cbv = (const float*)d_in[6];
  const float* pwq = (const float*)d_in[7];
  const float* pbq = (const float*)d_in[8];
  const float* pwk = (const float*)d_in[9];
  const float* pbk = (const float*)d_in[10];
  const float* pwv = (const float*)d_in[11];
  const float* pbv = (const float*)d_in[12];
  float* out = (float*)d_out;

  hipLaunchKernelGGL(fused_attn, dim3(256), dim3(1024), 0, stream,
                     x, cwq, cbq, cwk, cbk, cwv, cbv,
                     pwq, pbq, pwk, pbk, pwv, pbv, out);
}

// Round 6
// 29.654 us; speedup vs baseline: 1.4931x; 1.4931x over previous
//
#include <hip/hip_runtime.h>

#define CC 8
#define HW 4096
#define L2E 1.4426950408889634f

typedef __attribute__((ext_vector_type(4))) float f32x4;

// Single fused kernel: 256 blocks (4 batches x 64 pixel-tiles) x 1024 threads.
// Each block is self-sufficient (no inter-block deps, no workspace):
//   phase 1a: all threads compute (pk*log2e, pv) for 4 m's each -> kv[] LDS
//   phase 1b: all threads compute pq for their lane's pixel (+ keep xn[8] regs)
//   phase 1c: ALL 16 waves compute Gram + rowsum partials (4 px/thread, scalar)
//   phase 2 : 16 waves x 256-m segments; k/v fed by broadcast ds_read_b128
//   phase 3 : wave 0 combines PAM partials + CAM 8x8 softmax
//   phase 4 : waves 0-7 write the fused epilogue
// NOTE: no min-waves clause in launch_bounds -- round 5's (1024,4) capped
// VGPRs at 64 and spilled ~41 MB/dispatch to scratch (WRITE_SIZE counter).
__global__ __launch_bounds__(1024) void fused_attn(
    const float* __restrict__ x,
    const float* __restrict__ cwq, const float* __restrict__ cbq,
    const float* __restrict__ cwk, const float* __restrict__ cbk,
    const float* __restrict__ cwv, const float* __restrict__ cbv,
    const float* __restrict__ pwq, const float* __restrict__ pbq,
    const float* __restrict__ pwk, const float* __restrict__ pbk,
    const float* __restrict__ pwv, const float* __restrict__ pbv,
    float* __restrict__ out)
{
  const int b = blockIdx.x >> 6, tile = blockIdx.x & 63;
  const int n0 = tile * 64;
  const int t = threadIdx.x, ln = t & 63;
  const int wid = __builtin_amdgcn_readfirstlane(t >> 6);   // wave 0..15

  __shared__ __align__(16) float kv[HW * 2];                // 32 KB (k2,v interleaved)
  __shared__ float redd[16][64], redn[16][64];              // 8 KB
  __shared__ float gpart[16][44];                           // 2.75 KB
  __shared__ float sums[44], Gl[64], Ll[64], Al[64], Mp[64], cvs[8], outp[64];

  const float* xb = x + b * CC * HW;

  // ---- phase 1a: kv for my 4 m's (m = 4t..4t+3), coalesced float4 loads ----
  {
    const int m4 = t * 4;
    f32x4 xc[CC];
    #pragma unroll
    for (int c = 0; c < CC; ++c)
      xc[c] = *(const f32x4*)(xb + c * HW + m4);
    f32x4 kk, vv;
    #pragma unroll
    for (int j = 0; j < 4; ++j) {
      float k = pbk[0], v = pbv[0];
      #pragma unroll
      for (int c = 0; c < CC; ++c) {
        k = fmaf(pwk[c], xc[c][j], k);
        v = fmaf(pwv[c], xc[c][j], v);
      }
      kk[j] = k * L2E; vv[j] = v;
    }
    f32x4* kv4 = (f32x4*)kv;
    f32x4 w0, w1;
    w0[0] = kk[0]; w0[1] = vv[0]; w0[2] = kk[1]; w0[3] = vv[1];
    w1[0] = kk[2]; w1[1] = vv[2]; w1[2] = kk[3]; w1[3] = vv[3];
    kv4[2 * t] = w0; kv4[2 * t + 1] = w1;
  }

  // ---- phase 1b: pq for pixel n0+ln (all waves need it); keep xn for epilogue ----
  float xn[CC];
  #pragma unroll
  for (int c = 0; c < CC; ++c) xn[c] = xb[c * HW + n0 + ln];
  float a = pbq[0];
  #pragma unroll
  for (int c = 0; c < CC; ++c) a = fmaf(pwq[c], xn[c], a);

  // ---- phase 1c: Gram + rowsums over all 16 waves (4 px/thread, coalesced) ----
  {
    float acc[44];
    #pragma unroll
    for (int i = 0; i < 44; ++i) acc[i] = 0.f;
    #pragma unroll
    for (int j = 0; j < 4; ++j) {
      const int p = j * 1024 + t;                 // thread-consecutive: coalesced
      float xv[CC];
      #pragma unroll
      for (int c = 0; c < CC; ++c) xv[c] = xb[c * HW + p];
      int k = 0;
      #pragma unroll
      for (int c = 0; c < CC; ++c) {
        #pragma unroll
        for (int d = c; d < CC; ++d) { acc[k] = fmaf(xv[c], xv[d], acc[k]); ++k; }
      }
      #pragma unroll
      for (int c = 0; c < CC; ++c) acc[36 + c] += xv[c];
    }
    #pragma unroll
    for (int i = 0; i < 44; ++i) {
      float v = acc[i];
      #pragma unroll
      for (int off = 32; off > 0; off >>= 1) v += __shfl_xor(v, off, 64);
      acc[i] = v;
    }
    if (ln == 0) {
      #pragma unroll
      for (int i = 0; i < 44; ++i) gpart[wid][i] = acc[i];
    }
  }
  __syncthreads();

  // ---- phase 2: PAM rank-1 softmax; wave wid handles m in [wid*256, wid*256+256) ----
  {
    const f32x4* kvw = ((const f32x4*)kv) + (wid << 7);     // 128 f32x4 = 256 m
    float dA = 0, dB = 0, dC = 0, dD = 0;
    float nA = 0, nB = 0, nC = 0, nD = 0;
    #pragma unroll 2
    for (int i = 0; i < 128; i += 4) {
      const f32x4 p0 = kvw[i], p1 = kvw[i + 1], p2 = kvw[i + 2], p3 = kvw[i + 3];
      float e;
      e = __builtin_amdgcn_exp2f(a * p0[0]); dA += e; nA = fmaf(e, p0[1], nA);
      e = __builtin_amdgcn_exp2f(a * p0[2]); dA += e; nA = fmaf(e, p0[3], nA);
      e = __builtin_amdgcn_exp2f(a * p1[0]); dB += e; nB = fmaf(e, p1[1], nB);
      e = __builtin_amdgcn_exp2f(a * p1[2]); dB += e; nB = fmaf(e, p1[3], nB);
      e = __builtin_amdgcn_exp2f(a * p2[0]); dC += e; nC = fmaf(e, p2[1], nC);
      e = __builtin_amdgcn_exp2f(a * p2[2]); dC += e; nC = fmaf(e, p2[3], nC);
      e = __builtin_amdgcn_exp2f(a * p3[0]); dD += e; nD = fmaf(e, p3[1], nD);
      e = __builtin_amdgcn_exp2f(a * p3[2]); dD += e; nD = fmaf(e, p3[3], nD);
    }
    redd[wid][ln] = (dA + dB) + (dC + dD);
    redn[wid][ln] = (nA + nB) + (nC + nD);
  }
  __syncthreads();

  // ---- phase 3: wave 0: PAM combine + CAM 8x8 softmax ----
  if (t < 64) {
    float D = 0.f, N = 0.f;
    #pragma unroll
    for (int s = 0; s < 16; ++s) { D += redd[s][t]; N += redn[s][t]; }
    outp[t] = N / D;
  }
  if (t < 44) {
    float s = 0.f;
    #pragma unroll
    for (int w = 0; w < 16; ++w) s += gpart[w][t];
    sums[t] = s;
  }
  __syncthreads();

  const int c = ln >> 3, d = ln & 7;
  if (t < 64) {
    const int lo = min(c, d), hi = max(c, d);
    Gl[t] = sums[lo * 8 + hi - lo * (lo + 1) / 2];
  }
  __syncthreads();

  float Lv = 0.f;
  if (t < 64) {
    float qs = 0.f, ks = 0.f;
    #pragma unroll
    for (int e = 0; e < 8; ++e) {
      qs = fmaf(cwq[c * 8 + e], sums[36 + e], qs);
      ks = fmaf(cwk[d * 8 + e], sums[36 + e], ks);
    }
    float A = 0.f;
    #pragma unroll
    for (int e = 0; e < 8; ++e) {
      float inner = 0.f;
      #pragma unroll
      for (int f = 0; f < 8; ++f) inner = fmaf(Gl[e * 8 + f], cwk[d * 8 + f], inner);
      A = fmaf(cwq[c * 8 + e], inner, A);
    }
    Lv = A + qs * cbk[d] + cbq[c] * ks + 4096.f * cbq[c] * cbk[d];
    Ll[t] = Lv;
  }
  __syncthreads();

  if (t < 64) {
    float mx = -INFINITY;
    #pragma unroll
    for (int f = 0; f < 8; ++f) mx = fmaxf(mx, Ll[c * 8 + f]);
    float ssum = 0.f;
    #pragma unroll
    for (int f = 0; f < 8; ++f) ssum += __expf(Ll[c * 8 + f] - mx);
    Al[t] = __expf(Lv - mx) / ssum;
  }
  __syncthreads();

  if (t < 64) {
    float M = 0.f;
    #pragma unroll
    for (int f = 0; f < 8; ++f) M = fmaf(Al[c * 8 + f], cwv[f * 8 + d], M);
    if (d == c) M += 2.f;            // +2I: residual x appears in both CAM and PAM
    Mp[t] = M;
    if (d == 0) {
      float cvv = 0.f;
      #pragma unroll
      for (int f = 0; f < 8; ++f) cvv = fmaf(Al[c * 8 + f], cbv[f], cvv);
      cvs[c] = cvv;
    }
  }
  __syncthreads();

  // ---- phase 4: epilogue, waves 0-7: channel w for all 64 pixels (xn reused) ----
  if (t < 512) {
    const int w = wid;
    float o = cvs[w] + outp[ln];
    #pragma unroll
    for (int dd = 0; dd < 8; ++dd) o = fmaf(Mp[w * 8 + dd], xn[dd], o);
    out[(b * 8 + w) * HW + n0 + ln] = o;
  }
}

extern "C" void kernel_launch(void* const* d_in, const int* in_sizes, int n_in,
                              void* d_out, int out_size, void* d_ws, size_t ws_size,
                              hipStream_t stream) {
  const float* x   = (const float*)d_in[0];
  const float* cwq = (const float*)d_in[1];
  const float* cbq = (const float*)d_in[2];
  const float* cwk = (const float*)d_in[3];
  const float* cbk = (const float*)d_in[4];
  const float* cwv = (const float*)d_in[5];
  const float* cbv = (const float*)d_in[6];
  const float* pwq = (const float*)d_in[7];
  const float* pbq = (const float*)d_in[8];
  const float* pwk = (const float*)d_in[9];
  const float* pbk = (const float*)d_in[10];
  const float* pwv = (const float*)d_in[11];
  const float* pbv = (const float*)d_in[12];
  float* out = (float*)d_out;

  hipLaunchKernelGGL(fused_attn, dim3(256), dim3(1024), 0, stream,
                     x, cwq, cbq, cwk, cbk, cwv, cbv,
                     pwq, pbq, pwk, pbk, pwv, pbv, out);
}

// Round 7
// 23.231 us; speedup vs baseline: 1.9059x; 1.2765x over previous
//
#include <hip/hip_runtime.h>

#define CC 8
#define HW 4096
#define L2E 1.4426950408889634f
#define NG 256

// ws float offsets
#define GPART_OFF 0        // [4][16][44] Gram/rowsum partials
#define BMIN_OFF  2816     // [64] per-block pq min
#define BMAX_OFF  2880     // [64] per-block pq max
#define SSTAT_OFF 2944     // {smin, delta}
#define PQ_OFF    4096     // [4][4096] pq
#define KVQ_OFF   20480    // [4][4096] float4 {pk*log2e, pk, pv, pv*pk}
#define TAB_OFF   86016    // [4][256]  float4 {G, G', F, F'}

typedef __attribute__((ext_vector_type(4))) float f32x4;

#define WRED_ADD(v) { _Pragma("unroll") for (int _o = 32; _o > 0; _o >>= 1) v += __shfl_xor(v, _o, 64); }
#define WRED_MIN(v) { _Pragma("unroll") for (int _o = 32; _o > 0; _o >>= 1) v = fminf(v, __shfl_xor(v, _o, 64)); }
#define WRED_MAX(v) { _Pragma("unroll") for (int _o = 32; _o > 0; _o >>= 1) v = fmaxf(v, __shfl_xor(v, _o, 64)); }

// ---------------- Kernel A: pq/kvq vectors, Gram partials, pq min/max ----------------
__global__ __launch_bounds__(256) void kA(
    const float* __restrict__ x,
    const float* __restrict__ pwq, const float* __restrict__ pbq,
    const float* __restrict__ pwk, const float* __restrict__ pbk,
    const float* __restrict__ pwv, const float* __restrict__ pbv,
    float* __restrict__ ws)
{
  const int b = blockIdx.x >> 4, chunk = blockIdx.x & 15;
  const int t = threadIdx.x, ln = t & 63, wv = t >> 6;
  const int n = chunk * 256 + t;
  const float* xb = x + b * CC * HW;

  float xv[CC];
  #pragma unroll
  for (int c = 0; c < CC; ++c) xv[c] = xb[c * HW + n];

  float pq = pbq[0], pk = pbk[0], pv = pbv[0];
  #pragma unroll
  for (int c = 0; c < CC; ++c) {
    pq = fmaf(pwq[c], xv[c], pq);
    pk = fmaf(pwk[c], xv[c], pk);
    pv = fmaf(pwv[c], xv[c], pv);
  }
  ws[PQ_OFF + b * HW + n] = pq;
  f32x4 kq;
  kq[0] = pk * L2E; kq[1] = pk; kq[2] = pv; kq[3] = pv * pk;
  ((f32x4*)(ws + KVQ_OFF))[b * HW + n] = kq;

  float acc[44];
  {
    int k = 0;
    #pragma unroll
    for (int c = 0; c < CC; ++c) {
      #pragma unroll
      for (int d = c; d < CC; ++d) { acc[k] = xv[c] * xv[d]; ++k; }
    }
    #pragma unroll
    for (int c = 0; c < CC; ++c) acc[36 + c] = xv[c];
  }
  #pragma unroll
  for (int i = 0; i < 44; ++i) { float v = acc[i]; WRED_ADD(v); acc[i] = v; }
  float mn = pq, mx = pq;
  WRED_MIN(mn); WRED_MAX(mx);

  __shared__ float part[4][44], wmn[4], wmx[4];
  if (ln == 0) {
    #pragma unroll
    for (int i = 0; i < 44; ++i) part[wv][i] = acc[i];
    wmn[wv] = mn; wmx[wv] = mx;
  }
  __syncthreads();
  if (t < 44) {
    ws[GPART_OFF + (b * 16 + chunk) * 44 + t] =
        part[0][t] + part[1][t] + part[2][t] + part[3][t];
  }
  if (t == 0) {
    ws[BMIN_OFF + blockIdx.x] = fminf(fminf(wmn[0], wmn[1]), fminf(wmn[2], wmn[3]));
    ws[BMAX_OFF + blockIdx.x] = fmaxf(fmaxf(wmx[0], wmx[1]), fmaxf(wmx[2], wmx[3]));
  }
}

// ---------------- Kernel B: tabulate F,G,F',G' on the s-grid ----------------
// 256 blocks x 64 threads (1 wave). Block j: batch j>>6, grid points (j&63)*4..+3.
__global__ __launch_bounds__(64) void kB(const float* __restrict__ ws_c,
                                         float* __restrict__ ws)
{
  const int b = blockIdx.x >> 6, pg = blockIdx.x & 63;
  const int ln = threadIdx.x;

  // redundant global bounds reduction (64 entries, lane-parallel)
  float mn = ws_c[BMIN_OFF + ln];
  float mx = ws_c[BMAX_OFF + ln];
  WRED_MIN(mn); WRED_MAX(mx);
  const float smin = mn - 1e-4f;
  const float delta = fmaxf(mx + 1e-4f - smin, 1e-3f) / (float)(NG - 1);

  const float s0 = smin + delta * (float)(pg * 4 + 0);
  const float s1 = smin + delta * (float)(pg * 4 + 1);
  const float s2 = smin + delta * (float)(pg * 4 + 2);
  const float s3 = smin + delta * (float)(pg * 4 + 3);

  const f32x4* kq = ((const f32x4*)(ws_c + KVQ_OFF)) + b * HW;

  float G0 = 0, P0 = 0, F0 = 0, Q0 = 0;
  float G1 = 0, P1 = 0, F1 = 0, Q1 = 0;
  float G2 = 0, P2 = 0, F2 = 0, Q2 = 0;
  float G3 = 0, P3 = 0, F3 = 0, Q3 = 0;

  #pragma unroll 4
  for (int i = 0; i < 64; ++i) {
    const f32x4 q = kq[i * 64 + ln];
    float e;
    e = __builtin_amdgcn_exp2f(s0 * q[0]);
    G0 += e; P0 = fmaf(e, q[1], P0); F0 = fmaf(e, q[2], F0); Q0 = fmaf(e, q[3], Q0);
    e = __builtin_amdgcn_exp2f(s1 * q[0]);
    G1 += e; P1 = fmaf(e, q[1], P1); F1 = fmaf(e, q[2], F1); Q1 = fmaf(e, q[3], Q1);
    e = __builtin_amdgcn_exp2f(s2 * q[0]);
    G2 += e; P2 = fmaf(e, q[1], P2); F2 = fmaf(e, q[2], F2); Q2 = fmaf(e, q[3], Q2);
    e = __builtin_amdgcn_exp2f(s3 * q[0]);
    G3 += e; P3 = fmaf(e, q[1], P3); F3 = fmaf(e, q[2], F3); Q3 = fmaf(e, q[3], Q3);
  }

  WRED_ADD(G0); WRED_ADD(P0); WRED_ADD(F0); WRED_ADD(Q0);
  WRED_ADD(G1); WRED_ADD(P1); WRED_ADD(F1); WRED_ADD(Q1);
  WRED_ADD(G2); WRED_ADD(P2); WRED_ADD(F2); WRED_ADD(Q2);
  WRED_ADD(G3); WRED_ADD(P3); WRED_ADD(F3); WRED_ADD(Q3);

  if (ln == 0) {
    f32x4* tab = ((f32x4*)(ws + TAB_OFF)) + b * NG + pg * 4;
    f32x4 t0, t1, t2, t3;
    t0[0] = G0; t0[1] = P0; t0[2] = F0; t0[3] = Q0;
    t1[0] = G1; t1[1] = P1; t1[2] = F1; t1[3] = Q1;
    t2[0] = G2; t2[1] = P2; t2[2] = F2; t2[3] = Q2;
    t3[0] = G3; t3[1] = P3; t3[2] = F3; t3[3] = Q3;
    tab[0] = t0; tab[1] = t1; tab[2] = t2; tab[3] = t3;
    if (blockIdx.x == 0) { ws[SSTAT_OFF] = smin; ws[SSTAT_OFF + 1] = delta; }
  }
}

// ---------------- Kernel C: per-pixel Hermite interp + CAM + fused epilogue ----------
// 64 blocks x 256 threads. Block j: batch j>>4, pixels (j&15)*256..+255.
__global__ __launch_bounds__(256) void kC(
    const float* __restrict__ x,
    const float* __restrict__ cwq, const float* __restrict__ cbq,
    const float* __restrict__ cwk, const float* __restrict__ cbk,
    const float* __restrict__ cwv, const float* __restrict__ cbv,
    const float* __restrict__ ws, float* __restrict__ out)
{
  const int b = blockIdx.x >> 4;
  const int t = threadIdx.x, ln = t & 63;
  const int n = (blockIdx.x & 15) * 256 + t;

  __shared__ f32x4 tbl[NG];                               // 4 KB
  __shared__ float sums[44], Gl[64], Ll[64], Al[64], Mp[64], cvs[8];

  tbl[t] = ((const f32x4*)(ws + TAB_OFF))[b * NG + t];
  if (t < 44) {
    float s = 0.f;
    #pragma unroll
    for (int ch = 0; ch < 16; ++ch) s += ws[GPART_OFF + (b * 16 + ch) * 44 + t];
    sums[t] = s;
  }
  __syncthreads();

  const int c = ln >> 3, d = ln & 7;
  if (t < 64) {
    const int lo = min(c, d), hi = max(c, d);
    Gl[t] = sums[lo * 8 + hi - lo * (lo + 1) / 2];
  }
  __syncthreads();

  float Lv = 0.f;
  if (t < 64) {
    float qs = 0.f, ks = 0.f;
    #pragma unroll
    for (int e = 0; e < 8; ++e) {
      qs = fmaf(cwq[c * 8 + e], sums[36 + e], qs);
      ks = fmaf(cwk[d * 8 + e], sums[36 + e], ks);
    }
    float A = 0.f;
    #pragma unroll
    for (int e = 0; e < 8; ++e) {
      float inner = 0.f;
      #pragma unroll
      for (int f = 0; f < 8; ++f) inner = fmaf(Gl[e * 8 + f], cwk[d * 8 + f], inner);
      A = fmaf(cwq[c * 8 + e], inner, A);
    }
    Lv = A + qs * cbk[d] + cbq[c] * ks + 4096.f * cbq[c] * cbk[d];
    Ll[t] = Lv;
  }
  __syncthreads();

  if (t < 64) {
    float mx = -INFINITY;
    #pragma unroll
    for (int f = 0; f < 8; ++f) mx = fmaxf(mx, Ll[c * 8 + f]);
    float ssum = 0.f;
    #pragma unroll
    for (int f = 0; f < 8; ++f) ssum += __expf(Ll[c * 8 + f] - mx);
    Al[t] = __expf(Lv - mx) / ssum;
  }
  __syncthreads();

  if (t < 64) {
    float M = 0.f;
    #pragma unroll
    for (int f = 0; f < 8; ++f) M = fmaf(Al[c * 8 + f], cwv[f * 8 + d], M);
    if (d == c) M += 2.f;            // +2I: residual x appears in both CAM and PAM
    Mp[t] = M;
    if (d == 0) {
      float cvv = 0.f;
      #pragma unroll
      for (int f = 0; f < 8; ++f) cvv = fmaf(Al[c * 8 + f], cbv[f], cvv);
      cvs[c] = cvv;
    }
  }
  __syncthreads();

  // ---- per-pixel PAM via cubic Hermite on the tabulated F,G ----
  const float smin = ws[SSTAT_OFF];
  const float delta = ws[SSTAT_OFF + 1];
  const float pqn = ws[PQ_OFF + b * HW + n];
  float u = (pqn - smin) / delta;
  u = fminf(fmaxf(u, 0.f), (float)(NG - 1));
  int i0 = (int)u;
  i0 = min(i0, NG - 2);
  const float tf = u - (float)i0;
  const f32x4 c0 = tbl[i0], c1 = tbl[i0 + 1];
  const float omt = 1.f - tf;
  const float omt2 = omt * omt, t2 = tf * tf;
  const float h00 = (1.f + 2.f * tf) * omt2;
  const float h10 = tf * omt2;
  const float h01 = t2 * (3.f - 2.f * tf);
  const float h11 = t2 * (tf - 1.f);
  const float Gv = h00 * c0[0] + h10 * delta * c0[1] + h01 * c1[0] + h11 * delta * c1[1];
  const float Fv = h00 * c0[2] + h10 * delta * c0[3] + h01 * c1[2] + h11 * delta * c1[3];
  const float op = Fv / Gv;

  // ---- epilogue: out[c,n] = M'[c,:]·x[:,n] + cv[c] + op ----
  float xn[CC];
  #pragma unroll
  for (int dd = 0; dd < CC; ++dd) xn[dd] = x[(b * 8 + dd) * HW + n];
  #pragma unroll
  for (int cc = 0; cc < CC; ++cc) {
    float o = cvs[cc] + op;
    #pragma unroll
    for (int dd = 0; dd < CC; ++dd) o = fmaf(Mp[cc * 8 + dd], xn[dd], o);
    out[(b * 8 + cc) * HW + n] = o;
  }
}

extern "C" void kernel_launch(void* const* d_in, const int* in_sizes, int n_in,
                              void* d_out, int out_size, void* d_ws, size_t ws_size,
                              hipStream_t stream) {
  const float* x   = (const float*)d_in[0];
  const float* cwq = (const float*)d_in[1];
  const float* cbq = (const float*)d_in[2];
  const float* cwk = (const float*)d_in[3];
  const float* cbk = (const float*)d_in[4];
  const float* cwv = (const float*)d_in[5];
  const float* cbv = (const float*)d_in[6];
  const float* pwq = (const float*)d_in[7];
  const float* pbq = (const float*)d_in[8];
  const float* pwk = (const float*)d_in[9];
  const float* pbk = (const float*)d_in[10];
  const float* pwv = (const float*)d_in[11];
  const float* pbv = (const float*)d_in[12];
  float* ws  = (float*)d_ws;
  float* out = (float*)d_out;

  hipLaunchKernelGGL(kA, dim3(64), dim3(256), 0, stream,
                     x, pwq, pbq, pwk, pbk, pwv, pbv, ws);
  hipLaunchKernelGGL(kB, dim3(256), dim3(64), 0, stream, ws, ws);
  hipLaunchKernelGGL(kC, dim3(64), dim3(256), 0, stream,
                     x, cwq, cbq, cwk, cbk, cwv, cbv, ws, out);
}